// Round 1
// baseline (351.570 us; speedup 1.0000x reference)
//
#include <hip/hip_runtime.h>
#include <hip/hip_bf16.h>
#include <stdint.h>

#define Bb 4
#define SEQ 2048
#define Ee 1024
#define Hh 16
#define Dh 64
#define Mm (Bb*SEQ)   // 8192

typedef __attribute__((ext_vector_type(8))) short bfrag;   // 8 bf16 (4 VGPRs)
typedef __attribute__((ext_vector_type(4))) float f32x4;
typedef unsigned short u16;

__device__ __forceinline__ u16 f2bf(float x) {
  __hip_bfloat16 h = __float2bfloat16(x);
  return *reinterpret_cast<u16*>(&h);
}

__device__ __forceinline__ void gll16(const void* g, void* l) {
  __builtin_amdgcn_global_load_lds(
      (const __attribute__((address_space(1))) void*)g,
      (__attribute__((address_space(3))) void*)l, 16, 0, 0);
}

// ---------------- cast fp32 -> bf16 ----------------
__global__ __launch_bounds__(256) void cast_kernel(const float* __restrict__ in,
                                                   u16* __restrict__ out, int n4) {
  int i = blockIdx.x * blockDim.x + threadIdx.x;
  int st = gridDim.x * blockDim.x;
  for (; i < n4; i += st) {
    float4 v = reinterpret_cast<const float4*>(in)[i];
    ushort4 o;
    o.x = f2bf(v.x); o.y = f2bf(v.y); o.z = f2bf(v.z); o.w = f2bf(v.w);
    reinterpret_cast<ushort4*>(out)[i] = o;
  }
}

// ---------------- GEMM: C[m,f] = sum_e A[m,e] * W[f,e] + bias[f] ----------------
// 128x128 tile, BK=64, 4 waves (2x2 of 64x64). m97 structure.
// OUTMODE 0: bf16 out scattered to [B,H,S,D] (base + z*M*E), OUTMODE 1: fp32 out [M,N]
template<int OUTMODE>
__global__ __launch_bounds__(256) void gemm_bt(
    const u16* __restrict__ A,
    const u16* __restrict__ W0, const u16* __restrict__ W1, const u16* __restrict__ W2,
    const float* __restrict__ b0, const float* __restrict__ b1, const float* __restrict__ b2,
    void* __restrict__ outp, int K, int N)
{
  __shared__ __align__(16) u16 smem[16384];   // 32 KB: As[128*64] + Bs[128*64]
  u16* As = smem;
  u16* Bs = smem + 8192;
  const int tid  = threadIdx.x;
  const int lane = tid & 63;
  const int wid  = tid >> 6;
  const int bm = blockIdx.x * 128;
  const int bn = blockIdx.y * 128;
  const int z  = blockIdx.z;
  const u16*  Wp = (z == 0) ? W0 : (z == 1) ? W1 : W2;
  const float* bp = (z == 0) ? b0 : (z == 1) ? b1 : b2;
  const int wr = (wid >> 1) * 64, wc = (wid & 1) * 64;
  const int lr = lane & 15, lk = (lane >> 4) * 8;
  f32x4 acc[4][4] = {};

  for (int kt = 0; kt < K; kt += 64) {
    __syncthreads();
#pragma unroll
    for (int p = 0; p < 4; ++p) {
      int flat = p * 2048 + tid * 8;
      int r = flat >> 6, c = flat & 63;
      gll16(A + (size_t)(bm + r) * K + kt + c, As + flat);
    }
#pragma unroll
    for (int p = 0; p < 4; ++p) {
      int flat = p * 2048 + tid * 8;
      int r = flat >> 6, c = flat & 63;
      gll16(Wp + (size_t)(bn + r) * K + kt + c, Bs + flat);
    }
    __syncthreads();
#pragma unroll
    for (int kk = 0; kk < 2; ++kk) {
      bfrag a[4], b[4];
#pragma unroll
      for (int i = 0; i < 4; ++i)
        a[i] = *reinterpret_cast<const bfrag*>(&As[(wr + i * 16 + lr) * 64 + kk * 32 + lk]);
#pragma unroll
      for (int j = 0; j < 4; ++j)
        b[j] = *reinterpret_cast<const bfrag*>(&Bs[(wc + j * 16 + lr) * 64 + kk * 32 + lk]);
#pragma unroll
      for (int i = 0; i < 4; ++i)
#pragma unroll
        for (int j = 0; j < 4; ++j)
          acc[i][j] = __builtin_amdgcn_mfma_f32_16x16x32_bf16(a[i], b[j], acc[i][j], 0, 0, 0);
    }
  }

  float bias[4];
#pragma unroll
  for (int j = 0; j < 4; ++j) bias[j] = bp[bn + wc + j * 16 + (lane & 15)];

  if (OUTMODE == 0) {
    __syncthreads();
    u16* cst = smem;   // [128][128] bf16 = 32 KB
#pragma unroll
    for (int i = 0; i < 4; ++i)
#pragma unroll
      for (int j = 0; j < 4; ++j)
#pragma unroll
        for (int e = 0; e < 4; ++e)
          cst[(wr + i * 16 + (lane >> 4) * 4 + e) * 128 + wc + j * 16 + (lane & 15)] =
              f2bf(acc[i][j][e] + bias[j]);
    __syncthreads();
    u16* outb = (u16*)outp + (size_t)z * (size_t)Mm * Ee;
#pragma unroll
    for (int p = 0; p < 8; ++p) {
      int chunk = p * 256 + tid;        // 2048 chunks of 8 bf16
      int r = chunk >> 4;
      int c = (chunk & 15) * 8;
      int m = bm + r, f = bn + c;
      u16* dst = outb + ((((size_t)(m >> 11) * Hh + (f >> 6)) * SEQ + (m & 2047)) * Dh + (f & 63));
      *reinterpret_cast<bfrag*>(dst) = *reinterpret_cast<const bfrag*>(&cst[r * 128 + c]);
    }
  } else {
    float* outf = (float*)outp;
    float* cf = reinterpret_cast<float*>(smem);   // [64][128] fp32 = 32 KB
#pragma unroll
    for (int half = 0; half < 2; ++half) {
      __syncthreads();
      if ((wid >> 1) == half) {
#pragma unroll
        for (int i = 0; i < 4; ++i)
#pragma unroll
          for (int j = 0; j < 4; ++j)
#pragma unroll
            for (int e = 0; e < 4; ++e)
              cf[(i * 16 + (lane >> 4) * 4 + e) * 128 + wc + j * 16 + (lane & 15)] =
                  acc[i][j][e] + bias[j];
      }
      __syncthreads();
#pragma unroll
      for (int p = 0; p < 8; ++p) {
        int chunk = p * 256 + tid;      // 2048 float4 chunks
        int r = chunk >> 5;
        int c = (chunk & 31) * 4;
        *reinterpret_cast<float4*>(&outf[(size_t)(bm + half * 64 + r) * N + bn + c]) =
            *reinterpret_cast<const float4*>(&cf[r * 128 + c]);
      }
    }
  }
}

// ---------------- fused attention (softsign, no normalization) ----------------
// block: one (b,h), 128 q-rows; 4 waves x 32 rows. K/V tiles of 64 rows.
__global__ __launch_bounds__(256) void attn_kernel(
    const u16* __restrict__ qg, const u16* __restrict__ kg,
    const u16* __restrict__ vg, u16* __restrict__ ctx)
{
  // Ks [64][64] (8KB, linear for global_load_lds) | Vt [64(d)][80(k)] | P 4x[32][80]
  __shared__ __align__(16) u16 smem[4096 + 64 * 80 + 4 * 32 * 80];
  const int tid  = threadIdx.x;
  const int lane = tid & 63;
  const int wid  = tid >> 6;
  u16* Ks = smem;
  u16* Vt = smem + 4096;
  u16* Pw = smem + 4096 + 5120 + wid * (32 * 80);

  const int bh = blockIdx.y;          // b*16 + h
  const int q0 = blockIdx.x * 128;
  const u16* qb = qg + (size_t)bh * SEQ * Dh;
  const u16* kb = kg + (size_t)bh * SEQ * Dh;
  const u16* vb = vg + (size_t)bh * SEQ * Dh;
  const int lr = lane & 15, lk = (lane >> 4) * 8;

  // Q fragments held in registers for the whole block
  bfrag aq[2][2];
#pragma unroll
  for (int mi = 0; mi < 2; ++mi)
#pragma unroll
    for (int kk = 0; kk < 2; ++kk)
      aq[mi][kk] = *reinterpret_cast<const bfrag*>(
          &qb[(size_t)(q0 + wid * 32 + mi * 16 + lr) * Dh + kk * 32 + lk]);

  f32x4 o[2][4] = {};

  for (int kt = 0; kt < SEQ; kt += 64) {
    __syncthreads();
    // stage K tile linear via global_load_lds
#pragma unroll
    for (int p = 0; p < 2; ++p) {
      int flat = p * 2048 + tid * 8;
      int r = flat >> 6, c = flat & 63;
      gll16(kb + (size_t)(kt + r) * Dh + c, Ks + flat);
    }
    // stage V transposed (reg transpose) -> Vt[d][k]
#pragma unroll
    for (int p = 0; p < 2; ++p) {
      int idx = p * 256 + tid;          // 512: kr = idx&63, d0 = (idx>>6)*8
      int kr = idx & 63, d0 = (idx >> 6) * 8;
      bfrag vv = *reinterpret_cast<const bfrag*>(&vb[(size_t)(kt + kr) * Dh + d0]);
#pragma unroll
      for (int j = 0; j < 8; ++j) Vt[(d0 + j) * 80 + kr] = (u16)vv[j];
    }
    __syncthreads();

    // S = Q K^T  (raw dot; scaling folded into softsign)
    f32x4 s[2][4] = {};
#pragma unroll
    for (int kk = 0; kk < 2; ++kk) {
      bfrag bk[4];
#pragma unroll
      for (int n = 0; n < 4; ++n)
        bk[n] = *reinterpret_cast<const bfrag*>(&Ks[(n * 16 + lr) * 64 + kk * 32 + lk]);
#pragma unroll
      for (int mi = 0; mi < 2; ++mi)
#pragma unroll
        for (int n = 0; n < 4; ++n)
          s[mi][n] = __builtin_amdgcn_mfma_f32_16x16x32_bf16(aq[mi][kk], bk[n], s[mi][n], 0, 0, 0);
    }

    // softsign(s/8) = s/(8+|s|); write P to per-wave LDS in A-frag-readable layout
#pragma unroll
    for (int mi = 0; mi < 2; ++mi)
#pragma unroll
      for (int n = 0; n < 4; ++n)
#pragma unroll
        for (int e = 0; e < 4; ++e) {
          float sv = s[mi][n][e];
          float pv = sv * __builtin_amdgcn_rcpf(8.0f + __builtin_fabsf(sv));
          Pw[(mi * 16 + (lane >> 4) * 4 + e) * 80 + n * 16 + (lane & 15)] = f2bf(pv);
        }

    // O += P @ V
#pragma unroll
    for (int kk = 0; kk < 2; ++kk) {
      bfrag ap[2], bv[4];
#pragma unroll
      for (int mi = 0; mi < 2; ++mi)
        ap[mi] = *reinterpret_cast<const bfrag*>(&Pw[(mi * 16 + lr) * 80 + kk * 32 + lk]);
#pragma unroll
      for (int n = 0; n < 4; ++n)
        bv[n] = *reinterpret_cast<const bfrag*>(&Vt[(n * 16 + lr) * 80 + kk * 32 + lk]);
#pragma unroll
      for (int mi = 0; mi < 2; ++mi)
#pragma unroll
        for (int n = 0; n < 4; ++n)
          o[mi][n] = __builtin_amdgcn_mfma_f32_16x16x32_bf16(ap[mi], bv[n], o[mi][n], 0, 0, 0);
    }
  }

  // epilogue: ctx[b, s, h*64+d] bf16, coalesced via LDS
  __syncthreads();
  u16* cst = smem;   // [128][64]
#pragma unroll
  for (int mi = 0; mi < 2; ++mi)
#pragma unroll
    for (int n = 0; n < 4; ++n)
#pragma unroll
      for (int e = 0; e < 4; ++e)
        cst[(wid * 32 + mi * 16 + (lane >> 4) * 4 + e) * 64 + n * 16 + (lane & 15)] =
            f2bf(o[mi][n][e]);
  __syncthreads();
  const int b = bh >> 4, h = bh & 15;
#pragma unroll
  for (int p = 0; p < 4; ++p) {
    int chunk = p * 256 + tid;          // 1024 chunks of 8 bf16
    int r = chunk >> 3, c = (chunk & 7) * 8;
    u16* dst = ctx + ((size_t)(b * SEQ + q0 + r) * Ee + h * Dh + c);
    *reinterpret_cast<bfrag*>(dst) = *reinterpret_cast<const bfrag*>(&cst[r * 64 + c]);
  }
}

// ---------------- launch ----------------
extern "C" void kernel_launch(void* const* d_in, const int* in_sizes, int n_in,
                              void* d_out, int out_size, void* d_ws, size_t ws_size,
                              hipStream_t stream)
{
  const float* x  = (const float*)d_in[0];
  const float* Wq = (const float*)d_in[1];
  const float* bq = (const float*)d_in[2];
  const float* Wk = (const float*)d_in[3];
  const float* bk = (const float*)d_in[4];
  const float* Wv = (const float*)d_in[5];
  const float* bv = (const float*)d_in[6];
  const float* Wo = (const float*)d_in[7];
  const float* bo = (const float*)d_in[8];
  float* out = (float*)d_out;

  u16* ws  = (u16*)d_ws;
  u16* xb  = ws;                         // 8,388,608 elems
  u16* wqb = ws + 8388608;               // 1,048,576 each
  u16* wkb = wqb + 1048576;
  u16* wvb = wkb + 1048576;
  u16* wob = wvb + 1048576;
  u16* qkv = wob + 1048576;              // 3 x 8,388,608  [B,H,S,D]
  u16* ctx = qkv + (size_t)3 * 8388608;  // 8,388,608      [B,S,E]

  cast_kernel<<<2048, 256, 0, stream>>>(x,  xb,  8388608 / 4);
  cast_kernel<<<1024, 256, 0, stream>>>(Wq, wqb, 1048576 / 4);
  cast_kernel<<<1024, 256, 0, stream>>>(Wk, wkb, 1048576 / 4);
  cast_kernel<<<1024, 256, 0, stream>>>(Wv, wvb, 1048576 / 4);
  cast_kernel<<<1024, 256, 0, stream>>>(Wo, wob, 1048576 / 4);

  // Q,K,V projections (z picks weight/bias), bf16 out in [B,H,S,D]
  gemm_bt<0><<<dim3(64, 8, 3), 256, 0, stream>>>(xb, wqb, wkb, wvb, bq, bk, bv,
                                                 qkv, Ee, Ee);
  // fused softsign attention -> ctx [B,S,E] bf16
  attn_kernel<<<dim3(16, 64), 256, 0, stream>>>(qkv, qkv + 8388608, qkv + 2 * 8388608, ctx);
  // output projection, fp32 out
  gemm_bt<1><<<dim3(64, 8, 1), 256, 0, stream>>>(ctx, wob, wob, wob, bo, bo, bo,
                                                 out, Ee, Ee);
}

// Round 2
// 316.821 us; speedup vs baseline: 1.1097x; 1.1097x over previous
//
#include <hip/hip_runtime.h>
#include <hip/hip_bf16.h>
#include <stdint.h>

#define Bb 4
#define SEQ 2048
#define Ee 1024
#define Hh 16
#define Dh 64
#define Mm (Bb*SEQ)   // 8192

typedef __attribute__((ext_vector_type(8))) short bfrag;   // 8 bf16 (4 VGPRs)
typedef __attribute__((ext_vector_type(4))) float f32x4;
typedef unsigned short u16;

__device__ __forceinline__ u16 f2bf(float x) {
  __hip_bfloat16 h = __float2bfloat16(x);
  return *reinterpret_cast<u16*>(&h);
}

__device__ __forceinline__ void gll16(const void* g, void* l) {
  __builtin_amdgcn_global_load_lds(
      (const __attribute__((address_space(1))) void*)g,
      (__attribute__((address_space(3))) void*)l, 16, 0, 0);
}

// ---------------- fused cast fp32 -> bf16 (x, Wq, Wk, Wv, Wo in one dispatch) ----
// 4-elem units: x = 2097152 units, then 4 weight segments of 262144 units each.
__global__ __launch_bounds__(256) void cast_all(
    const float* __restrict__ x,  const float* __restrict__ wq,
    const float* __restrict__ wk, const float* __restrict__ wv,
    const float* __restrict__ wo,
    u16* __restrict__ xb, u16* __restrict__ wqb, u16* __restrict__ wkb,
    u16* __restrict__ wvb, u16* __restrict__ wob)
{
  int idx = blockIdx.x * 256 + threadIdx.x;
  const float* src; u16* dst; int off;
  if (idx < 2097152) { src = x; dst = xb; off = idx; }
  else {
    int t = idx - 2097152;
    int seg = t >> 18;             // 262144-unit segments
    off = t & 262143;
    src = (seg == 0) ? wq : (seg == 1) ? wk : (seg == 2) ? wv : wo;
    dst = (seg == 0) ? wqb : (seg == 1) ? wkb : (seg == 2) ? wvb : wob;
  }
  float4 v = reinterpret_cast<const float4*>(src)[off];
  ushort4 o;
  o.x = f2bf(v.x); o.y = f2bf(v.y); o.z = f2bf(v.z); o.w = f2bf(v.w);
  reinterpret_cast<ushort4*>(dst)[off] = o;
}

// ---------------- GEMM: C[m,f] = sum_e A[m,e] * W[f,e] + bias[f] ----------------
// 128x128 tile, BK=64, 4 waves (2x2 of 64x64). m97 structure (unchanged this round).
// OUTMODE 0: bf16 out scattered to [B,H,S,D] (base + z*M*E), OUTMODE 1: fp32 out [M,N]
template<int OUTMODE>
__global__ __launch_bounds__(256) void gemm_bt(
    const u16* __restrict__ A,
    const u16* __restrict__ W0, const u16* __restrict__ W1, const u16* __restrict__ W2,
    const float* __restrict__ b0, const float* __restrict__ b1, const float* __restrict__ b2,
    void* __restrict__ outp, int K, int N)
{
  __shared__ __align__(16) u16 smem[16384];   // 32 KB: As[128*64] + Bs[128*64]
  u16* As = smem;
  u16* Bs = smem + 8192;
  const int tid  = threadIdx.x;
  const int lane = tid & 63;
  const int wid  = tid >> 6;
  const int bm = blockIdx.x * 128;
  const int bn = blockIdx.y * 128;
  const int z  = blockIdx.z;
  const u16*  Wp = (z == 0) ? W0 : (z == 1) ? W1 : W2;
  const float* bp = (z == 0) ? b0 : (z == 1) ? b1 : b2;
  const int wr = (wid >> 1) * 64, wc = (wid & 1) * 64;
  const int lr = lane & 15, lk = (lane >> 4) * 8;
  f32x4 acc[4][4] = {};

  for (int kt = 0; kt < K; kt += 64) {
    __syncthreads();
#pragma unroll
    for (int p = 0; p < 4; ++p) {
      int flat = p * 2048 + tid * 8;
      int r = flat >> 6, c = flat & 63;
      gll16(A + (size_t)(bm + r) * K + kt + c, As + flat);
    }
#pragma unroll
    for (int p = 0; p < 4; ++p) {
      int flat = p * 2048 + tid * 8;
      int r = flat >> 6, c = flat & 63;
      gll16(Wp + (size_t)(bn + r) * K + kt + c, Bs + flat);
    }
    __syncthreads();
#pragma unroll
    for (int kk = 0; kk < 2; ++kk) {
      bfrag a[4], b[4];
#pragma unroll
      for (int i = 0; i < 4; ++i)
        a[i] = *reinterpret_cast<const bfrag*>(&As[(wr + i * 16 + lr) * 64 + kk * 32 + lk]);
#pragma unroll
      for (int j = 0; j < 4; ++j)
        b[j] = *reinterpret_cast<const bfrag*>(&Bs[(wc + j * 16 + lr) * 64 + kk * 32 + lk]);
#pragma unroll
      for (int i = 0; i < 4; ++i)
#pragma unroll
        for (int j = 0; j < 4; ++j)
          acc[i][j] = __builtin_amdgcn_mfma_f32_16x16x32_bf16(a[i], b[j], acc[i][j], 0, 0, 0);
    }
  }

  float bias[4];
#pragma unroll
  for (int j = 0; j < 4; ++j) bias[j] = bp[bn + wc + j * 16 + (lane & 15)];

  if (OUTMODE == 0) {
    __syncthreads();
    u16* cst = smem;   // [128][128] bf16 = 32 KB
#pragma unroll
    for (int i = 0; i < 4; ++i)
#pragma unroll
      for (int j = 0; j < 4; ++j)
#pragma unroll
        for (int e = 0; e < 4; ++e)
          cst[(wr + i * 16 + (lane >> 4) * 4 + e) * 128 + wc + j * 16 + (lane & 15)] =
              f2bf(acc[i][j][e] + bias[j]);
    __syncthreads();
    u16* outb = (u16*)outp + (size_t)z * (size_t)Mm * Ee;
#pragma unroll
    for (int p = 0; p < 8; ++p) {
      int chunk = p * 256 + tid;        // 2048 chunks of 8 bf16
      int r = chunk >> 4;
      int c = (chunk & 15) * 8;
      int m = bm + r, f = bn + c;
      u16* dst = outb + ((((size_t)(m >> 11) * Hh + (f >> 6)) * SEQ + (m & 2047)) * Dh + (f & 63));
      *reinterpret_cast<bfrag*>(dst) = *reinterpret_cast<const bfrag*>(&cst[r * 128 + c]);
    }
  } else {
    float* outf = (float*)outp;
    float* cf = reinterpret_cast<float*>(smem);   // [64][128] fp32 = 32 KB
#pragma unroll
    for (int half = 0; half < 2; ++half) {
      __syncthreads();
      if ((wid >> 1) == half) {
#pragma unroll
        for (int i = 0; i < 4; ++i)
#pragma unroll
          for (int j = 0; j < 4; ++j)
#pragma unroll
            for (int e = 0; e < 4; ++e)
              cf[(i * 16 + (lane >> 4) * 4 + e) * 128 + wc + j * 16 + (lane & 15)] =
                  acc[i][j][e] + bias[j];
      }
      __syncthreads();
#pragma unroll
      for (int p = 0; p < 8; ++p) {
        int chunk = p * 256 + tid;      // 2048 float4 chunks
        int r = chunk >> 5;
        int c = (chunk & 31) * 4;
        *reinterpret_cast<float4*>(&outf[(size_t)(bm + half * 64 + r) * N + bn + c]) =
            *reinterpret_cast<const float4*>(&cf[r * 128 + c]);
      }
    }
  }
}

// ---------------- V transpose: [B,H,S,D] -> [B,H,D,S] (swizzled LDS tile) --------
// block = one bh x 128-row s-tile. LDS [128 s][64 d], phys col = d ^ ((s>>3)&7)<<3.
__global__ __launch_bounds__(256) void transpose_v(const u16* __restrict__ v,
                                                   u16* __restrict__ vt)
{
  __shared__ __align__(16) u16 lds[8192];   // 16 KB
  const int tid = threadIdx.x;
  const int bh = blockIdx.y;
  const int st = blockIdx.x * 128;
  const u16* vb = v + (size_t)bh * SEQ * Dh;
#pragma unroll
  for (int p = 0; p < 4; ++p) {
    int flat = p * 2048 + tid * 8;
    int s = flat >> 6, dp = flat & 63;
    int dl = dp ^ (((s >> 3) & 7) << 3);        // pre-swizzled global source
    gll16(vb + (size_t)(st + s) * Dh + dl, lds + flat);
  }
  __syncthreads();
  u16* vtb = vt + (size_t)bh * Dh * SEQ;
#pragma unroll
  for (int p = 0; p < 4; ++p) {
    int chunk = p * 256 + tid;      // 1024 chunks: sc = chunk&15, d = chunk>>4
    int sc = chunk & 15, d = chunk >> 4;
    int X = (sc & 7) << 3;
    bfrag o;
#pragma unroll
    for (int e = 0; e < 8; ++e)
      o[e] = (short)lds[(sc * 8 + e) * 64 + (d ^ X)];
    *reinterpret_cast<bfrag*>(&vtb[(size_t)d * SEQ + st + sc * 8]) = o;
  }
}

// ---------------- fused attention (softsign, no normalization) ----------------
// block: one (b,h) x 128 q-rows; 4 waves x 32 rows. K/V tiles 64 wide, double-buffered,
// XOR-swizzled LDS (pre-swizzled global source feeding global_load_lds).
__global__ __launch_bounds__(256) void attn_kernel(
    const u16* __restrict__ qg, const u16* __restrict__ kg,
    const u16* __restrict__ vtg, u16* __restrict__ ctx)
{
  // Kb[2] @0 (4096 each) | Vb[2] @8192 (4096 each) | P @16384 (4 waves x 2048)
  __shared__ __align__(16) u16 smem[24576];   // 48 KB -> 3 blocks/CU
  const int tid  = threadIdx.x;
  const int lane = tid & 63;
  const int wid  = tid >> 6;
  const int lr = lane & 15, lk = (lane >> 4) * 8;
  const int g = lane >> 4, c = lane & 15;

  // XCD-bijective swizzle: XCD x owns bh range [x*8, x*8+8) (nwg=1024, %8==0)
  const int orig = blockIdx.y * 16 + blockIdx.x;
  const int swz  = (orig & 7) * 128 + (orig >> 3);
  const int q0 = (swz & 15) * 128;
  const int bh = swz >> 4;

  const u16* qb  = qg  + (size_t)bh * SEQ * Dh;
  const u16* kb  = kg  + (size_t)bh * SEQ * Dh;
  const u16* vtb = vtg + (size_t)bh * Dh * SEQ;
  u16* Pw = smem + 16384 + wid * 2048;

  // Q fragments in registers for the whole block
  bfrag aq[2][2];
#pragma unroll
  for (int mi = 0; mi < 2; ++mi)
#pragma unroll
    for (int kk = 0; kk < 2; ++kk)
      aq[mi][kk] = *reinterpret_cast<const bfrag*>(
          &qb[(size_t)(q0 + wid * 32 + mi * 16 + lr) * Dh + kk * 32 + lk]);

  f32x4 o[2][4] = {};

  auto stage = [&](int kt, int buf) {
#pragma unroll
    for (int p = 0; p < 2; ++p) {
      int flat = p * 2048 + tid * 8;
      int r = flat >> 6, cp = flat & 63;
      int cl = cp ^ ((r & 7) << 3);             // pre-swizzled source col
      gll16(kb + (size_t)(kt + r) * Dh + cl, smem + buf * 4096 + flat);
    }
#pragma unroll
    for (int p = 0; p < 2; ++p) {
      int flat = p * 2048 + tid * 8;
      int r = flat >> 6, cp = flat & 63;        // r = d row of Vt tile
      int cl = cp ^ ((r & 7) << 3);
      gll16(vtb + (size_t)r * SEQ + kt + cl, smem + 8192 + buf * 4096 + flat);
    }
  };

  stage(0, 0);
  __syncthreads();

  for (int ti = 0; ti < 32; ++ti) {
    const int cur = ti & 1;
    if (ti < 31) stage((ti + 1) * 64, cur ^ 1);   // prefetch overlaps compute
    const u16* Kb = smem + cur * 4096;
    const u16* Vb = smem + 8192 + cur * 4096;

    // S = Q K^T  (scaling folded into softsign)
    f32x4 s[2][4] = {};
#pragma unroll
    for (int kk = 0; kk < 2; ++kk) {
      bfrag bk[4];
#pragma unroll
      for (int n = 0; n < 4; ++n) {
        int row = n * 16 + lr;
        bk[n] = *reinterpret_cast<const bfrag*>(
            &Kb[row * 64 + ((kk * 32 + lk) ^ ((row & 7) << 3))]);
      }
#pragma unroll
      for (int mi = 0; mi < 2; ++mi)
#pragma unroll
        for (int n = 0; n < 4; ++n)
          s[mi][n] = __builtin_amdgcn_mfma_f32_16x16x32_bf16(aq[mi][kk], bk[n], s[mi][n], 0, 0, 0);
    }

    // softsign(s/8) = s/(8+|s|); P to per-wave swizzled LDS
#pragma unroll
    for (int mi = 0; mi < 2; ++mi)
#pragma unroll
      for (int n = 0; n < 4; ++n)
#pragma unroll
        for (int e = 0; e < 4; ++e) {
          int prow = mi * 16 + g * 4 + e;
          float sv = s[mi][n][e];
          float pv = sv * __builtin_amdgcn_rcpf(8.0f + __builtin_fabsf(sv));
          Pw[prow * 64 + ((n * 16 + c) ^ ((prow & 7) << 3))] = f2bf(pv);
        }

    // O += P @ V
#pragma unroll
    for (int kk = 0; kk < 2; ++kk) {
      bfrag ap[2], bv[4];
#pragma unroll
      for (int mi = 0; mi < 2; ++mi) {
        int row = mi * 16 + lr;
        ap[mi] = *reinterpret_cast<const bfrag*>(
            &Pw[row * 64 + ((kk * 32 + lk) ^ ((row & 7) << 3))]);
      }
#pragma unroll
      for (int n = 0; n < 4; ++n) {
        int row = n * 16 + lr;
        bv[n] = *reinterpret_cast<const bfrag*>(
            &Vb[row * 64 + ((kk * 32 + lk) ^ ((row & 7) << 3))]);
      }
#pragma unroll
      for (int mi = 0; mi < 2; ++mi)
#pragma unroll
        for (int n = 0; n < 4; ++n)
          o[mi][n] = __builtin_amdgcn_mfma_f32_16x16x32_bf16(ap[mi], bv[n], o[mi][n], 0, 0, 0);
    }
    __syncthreads();   // drains prefetch vmcnt + releases buffers
  }

  // epilogue: ctx[b, s, h*64+d] bf16, coalesced via LDS
  u16* cst = smem;   // [128][64]
#pragma unroll
  for (int mi = 0; mi < 2; ++mi)
#pragma unroll
    for (int n = 0; n < 4; ++n)
#pragma unroll
      for (int e = 0; e < 4; ++e)
        cst[(wid * 32 + mi * 16 + g * 4 + e) * 64 + n * 16 + c] = f2bf(o[mi][n][e]);
  __syncthreads();
  const int b = bh >> 4, h = bh & 15;
#pragma unroll
  for (int p = 0; p < 4; ++p) {
    int chunk = p * 256 + tid;          // 1024 chunks of 8 bf16
    int r = chunk >> 3, cc = (chunk & 7) * 8;
    u16* dst = ctx + ((size_t)(b * SEQ + q0 + r) * Ee + h * Dh + cc);
    *reinterpret_cast<bfrag*>(dst) = *reinterpret_cast<const bfrag*>(&cst[r * 64 + cc]);
  }
}

// ---------------- launch ----------------
extern "C" void kernel_launch(void* const* d_in, const int* in_sizes, int n_in,
                              void* d_out, int out_size, void* d_ws, size_t ws_size,
                              hipStream_t stream)
{
  const float* x  = (const float*)d_in[0];
  const float* Wq = (const float*)d_in[1];
  const float* bq = (const float*)d_in[2];
  const float* Wk = (const float*)d_in[3];
  const float* bk = (const float*)d_in[4];
  const float* Wv = (const float*)d_in[5];
  const float* bv = (const float*)d_in[6];
  const float* Wo = (const float*)d_in[7];
  const float* bo = (const float*)d_in[8];
  float* out = (float*)d_out;

  u16* ws  = (u16*)d_ws;
  u16* xb  = ws;                         // 8,388,608 elems (dead after QKV GEMM)
  u16* wqb = ws + 8388608;               // 1,048,576 each
  u16* wkb = wqb + 1048576;
  u16* wvb = wkb + 1048576;
  u16* wob = wvb + 1048576;
  u16* qkv = wob + 1048576;              // 3 x 8,388,608  [B,H,S,D]
  u16* q_  = qkv;
  u16* k_  = qkv + 8388608;
  u16* v_  = qkv + 2 * 8388608;
  u16* vt  = xb;                         // reuse xb region: Vt [B,H,D,S]
  u16* ctx = v_;                         // reuse V region after transpose

  cast_all<<<12288, 256, 0, stream>>>(x, Wq, Wk, Wv, Wo, xb, wqb, wkb, wvb, wob);

  // Q,K,V projections (z picks weight/bias), bf16 out in [B,H,S,D]
  gemm_bt<0><<<dim3(64, 8, 3), 256, 0, stream>>>(xb, wqb, wkb, wvb, bq, bk, bv,
                                                 qkv, Ee, Ee);
  // V -> V^T [B,H,D,S] (once; attn would otherwise re-transpose 16x per bh)
  transpose_v<<<dim3(16, 64), 256, 0, stream>>>(v_, vt);
  // fused softsign attention -> ctx [B,S,E] bf16
  attn_kernel<<<dim3(16, 64), 256, 0, stream>>>(q_, k_, vt, ctx);
  // output projection, fp32 out
  gemm_bt<1><<<dim3(64, 8, 1), 256, 0, stream>>>(ctx, wob, wob, wob, bo, bo, bo,
                                                 out, Ee, Ee);
}

// Round 3
// 305.359 us; speedup vs baseline: 1.1513x; 1.0375x over previous
//
#include <hip/hip_runtime.h>
#include <hip/hip_bf16.h>
#include <stdint.h>

#define Bb 4
#define SEQ 2048
#define Ee 1024
#define Hh 16
#define Dh 64
#define Mm (Bb*SEQ)   // 8192

typedef __attribute__((ext_vector_type(8))) short bfrag;    // 8 bf16 (4 VGPRs)
typedef __attribute__((ext_vector_type(4))) float f32x4;
typedef __attribute__((ext_vector_type(16))) float f32x16;
typedef unsigned short u16;

__device__ __forceinline__ u16 f2bf(float x) {
  __hip_bfloat16 h = __float2bfloat16(x);
  return *reinterpret_cast<u16*>(&h);
}

__device__ __forceinline__ void gll16(const void* g, void* l) {
  __builtin_amdgcn_global_load_lds(
      (const __attribute__((address_space(1))) void*)g,
      (__attribute__((address_space(3))) void*)l, 16, 0, 0);
}

// ---------------- fused cast fp32 -> bf16 ----------------
__global__ __launch_bounds__(256) void cast_all(
    const float* __restrict__ x,  const float* __restrict__ wq,
    const float* __restrict__ wk, const float* __restrict__ wv,
    const float* __restrict__ wo,
    u16* __restrict__ xb, u16* __restrict__ wqb, u16* __restrict__ wkb,
    u16* __restrict__ wvb, u16* __restrict__ wob)
{
  int idx = blockIdx.x * 256 + threadIdx.x;
  const float* src; u16* dst; int off;
  if (idx < 2097152) { src = x; dst = xb; off = idx; }
  else {
    int t = idx - 2097152;
    int seg = t >> 18;
    off = t & 262143;
    src = (seg == 0) ? wq : (seg == 1) ? wk : (seg == 2) ? wv : wo;
    dst = (seg == 0) ? wqb : (seg == 1) ? wkb : (seg == 2) ? wvb : wob;
  }
  float4 v = reinterpret_cast<const float4*>(src)[off];
  ushort4 o;
  o.x = f2bf(v.x); o.y = f2bf(v.y); o.z = f2bf(v.z); o.w = f2bf(v.w);
  reinterpret_cast<ushort4*>(dst)[off] = o;
}

// ---------------- GEMM (m97 structure, unchanged) ----------------
template<int OUTMODE>
__global__ __launch_bounds__(256) void gemm_bt(
    const u16* __restrict__ A,
    const u16* __restrict__ W0, const u16* __restrict__ W1, const u16* __restrict__ W2,
    const float* __restrict__ b0, const float* __restrict__ b1, const float* __restrict__ b2,
    void* __restrict__ outp, int K, int N)
{
  __shared__ __align__(16) u16 smem[16384];
  u16* As = smem;
  u16* Bs = smem + 8192;
  const int tid  = threadIdx.x;
  const int lane = tid & 63;
  const int wid  = tid >> 6;
  const int bm = blockIdx.x * 128;
  const int bn = blockIdx.y * 128;
  const int z  = blockIdx.z;
  const u16*  Wp = (z == 0) ? W0 : (z == 1) ? W1 : W2;
  const float* bp = (z == 0) ? b0 : (z == 1) ? b1 : b2;
  const int wr = (wid >> 1) * 64, wc = (wid & 1) * 64;
  const int lr = lane & 15, lk = (lane >> 4) * 8;
  f32x4 acc[4][4] = {};

  for (int kt = 0; kt < K; kt += 64) {
    __syncthreads();
#pragma unroll
    for (int p = 0; p < 4; ++p) {
      int flat = p * 2048 + tid * 8;
      int r = flat >> 6, c = flat & 63;
      gll16(A + (size_t)(bm + r) * K + kt + c, As + flat);
    }
#pragma unroll
    for (int p = 0; p < 4; ++p) {
      int flat = p * 2048 + tid * 8;
      int r = flat >> 6, c = flat & 63;
      gll16(Wp + (size_t)(bn + r) * K + kt + c, Bs + flat);
    }
    __syncthreads();
#pragma unroll
    for (int kk = 0; kk < 2; ++kk) {
      bfrag a[4], b[4];
#pragma unroll
      for (int i = 0; i < 4; ++i)
        a[i] = *reinterpret_cast<const bfrag*>(&As[(wr + i * 16 + lr) * 64 + kk * 32 + lk]);
#pragma unroll
      for (int j = 0; j < 4; ++j)
        b[j] = *reinterpret_cast<const bfrag*>(&Bs[(wc + j * 16 + lr) * 64 + kk * 32 + lk]);
#pragma unroll
      for (int i = 0; i < 4; ++i)
#pragma unroll
        for (int j = 0; j < 4; ++j)
          acc[i][j] = __builtin_amdgcn_mfma_f32_16x16x32_bf16(a[i], b[j], acc[i][j], 0, 0, 0);
    }
  }

  float bias[4];
#pragma unroll
  for (int j = 0; j < 4; ++j) bias[j] = bp[bn + wc + j * 16 + (lane & 15)];

  if (OUTMODE == 0) {
    __syncthreads();
    u16* cst = smem;
#pragma unroll
    for (int i = 0; i < 4; ++i)
#pragma unroll
      for (int j = 0; j < 4; ++j)
#pragma unroll
        for (int e = 0; e < 4; ++e)
          cst[(wr + i * 16 + (lane >> 4) * 4 + e) * 128 + wc + j * 16 + (lane & 15)] =
              f2bf(acc[i][j][e] + bias[j]);
    __syncthreads();
    u16* outb = (u16*)outp + (size_t)z * (size_t)Mm * Ee;
#pragma unroll
    for (int p = 0; p < 8; ++p) {
      int chunk = p * 256 + tid;
      int r = chunk >> 4;
      int c = (chunk & 15) * 8;
      int m = bm + r, f = bn + c;
      u16* dst = outb + ((((size_t)(m >> 11) * Hh + (f >> 6)) * SEQ + (m & 2047)) * Dh + (f & 63));
      *reinterpret_cast<bfrag*>(dst) = *reinterpret_cast<const bfrag*>(&cst[r * 128 + c]);
    }
  } else {
    float* outf = (float*)outp;
    float* cf = reinterpret_cast<float*>(smem);
#pragma unroll
    for (int half = 0; half < 2; ++half) {
      __syncthreads();
      if ((wid >> 1) == half) {
#pragma unroll
        for (int i = 0; i < 4; ++i)
#pragma unroll
          for (int j = 0; j < 4; ++j)
#pragma unroll
            for (int e = 0; e < 4; ++e)
              cf[(i * 16 + (lane >> 4) * 4 + e) * 128 + wc + j * 16 + (lane & 15)] =
                  acc[i][j][e] + bias[j];
      }
      __syncthreads();
#pragma unroll
      for (int p = 0; p < 8; ++p) {
        int chunk = p * 256 + tid;
        int r = chunk >> 5;
        int c = (chunk & 31) * 4;
        *reinterpret_cast<float4*>(&outf[(size_t)(bm + half * 64 + r) * N + bn + c]) =
            *reinterpret_cast<const float4*>(&cf[r * 128 + c]);
      }
    }
  }
}

// ---------------- V transpose+permute: [B,H,S,D] -> [B,H,D,S'] -----------------
// s' = s with bits 2,3 swapped (involution). This bakes the PV k-permutation so
// the swapped-QK^T output registers feed PV's A-operand with NO cross-lane ops.
__global__ __launch_bounds__(256) void transpose_v(const u16* __restrict__ v,
                                                   u16* __restrict__ vt)
{
  __shared__ __align__(16) u16 lds[8192];
  const int tid = threadIdx.x;
  const int bh = blockIdx.y;
  const int st = blockIdx.x * 128;
  const u16* vb = v + (size_t)bh * SEQ * Dh;
#pragma unroll
  for (int p = 0; p < 4; ++p) {
    int flat = p * 2048 + tid * 8;
    int s = flat >> 6, dp = flat & 63;
    int dl = dp ^ (((s >> 3) & 7) << 3);        // pre-swizzled global source
    gll16(vb + (size_t)(st + s) * Dh + dl, lds + flat);
  }
  __syncthreads();
  u16* vtb = vt + (size_t)bh * Dh * SEQ;
#pragma unroll
  for (int p = 0; p < 4; ++p) {
    int chunk = p * 256 + tid;      // sc = chunk&15 (s'-octet), d = chunk>>4
    int sc = chunk & 15, d = chunk >> 4;
    bfrag o;
#pragma unroll
    for (int e = 0; e < 8; ++e) {
      int sp = sc * 8 + e;                              // s' local
      int ss = (sp & 0x63) | ((sp & 4) << 1) | ((sp & 8) >> 1) | (sp & 0x70);
      // swap bits 2 and 3 of sp:
      ss = (sp & ~12) | ((sp & 4) << 1) | ((sp & 8) >> 1);
      int X = ((ss >> 3) & 7) << 3;
      o[e] = (short)lds[ss * 64 + (d ^ X)];
    }
    *reinterpret_cast<bfrag*>(&vtb[(size_t)d * SEQ + st + sc * 8]) = o;
  }
}

// ---------------- fused attention (softsign), swapped-QK^T 32x32 ---------------
// block: one (b,h) x 256 q-rows; 4 waves x 64 q. K/V tiles of 64, double-buffered.
// S^T = mfma(K, Q) -> lane owns q=lane&31; softsign+cvt in-register; PV A-frag =
// S^T regs verbatim (V k-rows pre-permuted by transpose_v). No P LDS traffic.
__global__ __launch_bounds__(256) void attn_kernel(
    const u16* __restrict__ qg_, const u16* __restrict__ kg,
    const u16* __restrict__ vtg, u16* __restrict__ ctx)
{
  // K dbuf 2x4096 u16 | Vtp dbuf 2x4096 u16 = 32 KB; epilogue reuses as [256][64]
  __shared__ __align__(16) u16 smem[16384];
  const int tid  = threadIdx.x;
  const int lane = tid & 63;
  const int wid  = tid >> 6;
  const int ql = lane & 31;
  const int hi = lane >> 5;

  // XCD-bijective swizzle: 512 wgs, 64 per XCD -> 8 consecutive bh per XCD (K/V L2-fit)
  const int orig = blockIdx.x;
  const int swz  = (orig & 7) * 64 + (orig >> 3);
  const int bh = swz >> 3;
  const int q0 = (swz & 7) * 256;

  const u16* qb  = qg_ + (size_t)bh * SEQ * Dh;
  const u16* kb  = kg  + (size_t)bh * SEQ * Dh;
  const u16* vtb = vtg + (size_t)bh * Dh * SEQ;

  // Q held in registers: B-operand frags, qf[qg][db]: lane -> Q[q][db*16+hi*8..+7]
  bfrag qf[2][4];
#pragma unroll
  for (int qg2 = 0; qg2 < 2; ++qg2)
#pragma unroll
    for (int db = 0; db < 4; ++db)
      qf[qg2][db] = *reinterpret_cast<const bfrag*>(
          &qb[(size_t)(q0 + wid * 64 + qg2 * 32 + ql) * Dh + db * 16 + hi * 8]);

  f32x16 o[2][2] = {};   // o[qg][dh]

  auto stage = [&](int kt, int buf) {
#pragma unroll
    for (int p = 0; p < 2; ++p) {
      int flat = p * 2048 + tid * 8;
      int r = flat >> 6, cp = flat & 63;
      int cl = cp ^ ((r & 7) << 3);
      gll16(kb + (size_t)(kt + r) * Dh + cl, smem + buf * 4096 + flat);
    }
#pragma unroll
    for (int p = 0; p < 2; ++p) {
      int flat = p * 2048 + tid * 8;
      int r = flat >> 6, cp = flat & 63;       // r = d row of Vtp tile
      int cl = cp ^ ((r & 7) << 3);
      gll16(vtb + (size_t)r * SEQ + kt + cl, smem + 8192 + buf * 4096 + flat);
    }
  };

  stage(0, 0);
  __syncthreads();

  for (int ti = 0; ti < 32; ++ti) {
    const int cur = ti & 1;
    if (ti < 31) stage((ti + 1) * 64, cur ^ 1);   // prefetch overlaps compute
    const u16* Kb = smem + cur * 4096;
    const u16* Vb = smem + 8192 + cur * 4096;

#pragma unroll
    for (int kh = 0; kh < 2; ++kh) {
      // S^T[k][q] = mfma(A=K, B=Q), accumulated over 4 d-blocks
      f32x16 s[2] = {};
      const int krow = kh * 32 + ql;
      const int ksw = (krow & 7) << 3;
#pragma unroll
      for (int db = 0; db < 4; ++db) {
        bfrag ka = *reinterpret_cast<const bfrag*>(
            &Kb[krow * 64 + ((db * 16 + hi * 8) ^ ksw)]);
        s[0] = __builtin_amdgcn_mfma_f32_32x32x16_bf16(ka, qf[0][db], s[0], 0, 0, 0);
        s[1] = __builtin_amdgcn_mfma_f32_32x32x16_bf16(ka, qf[1][db], s[1], 0, 0, 0);
      }
      // softsign(s/8) = s/(8+|s|), cvt to bf16 in-register -> PV A-frags
      bfrag pa[2][2];
#pragma unroll
      for (int qg2 = 0; qg2 < 2; ++qg2)
#pragma unroll
        for (int r = 0; r < 16; ++r) {
          float sv = s[qg2][r];
          float pv = sv * __builtin_amdgcn_rcpf(8.0f + __builtin_fabsf(sv));
          pa[qg2][r >> 3][r & 7] = (short)f2bf(pv);
        }
      // O += P @ V (V rows pre-permuted to match S^T register order)
#pragma unroll
      for (int tt = 0; tt < 2; ++tt)
#pragma unroll
        for (int dh = 0; dh < 2; ++dh) {
          const int vrow = dh * 32 + ql;
          bfrag vb = *reinterpret_cast<const bfrag*>(
              &Vb[vrow * 64 + ((kh * 32 + tt * 16 + hi * 8) ^ ((vrow & 7) << 3))]);
          o[0][dh] = __builtin_amdgcn_mfma_f32_32x32x16_bf16(pa[0][tt], vb, o[0][dh], 0, 0, 0);
          o[1][dh] = __builtin_amdgcn_mfma_f32_32x32x16_bf16(pa[1][tt], vb, o[1][dh], 0, 0, 0);
        }
    }
    __syncthreads();   // drains prefetch vmcnt + releases buffers
  }

  // epilogue: O lane layout col d=ql, rows q=(r&3)+8*(r>>2)+4*hi; via LDS to coalesce
  u16* cst = smem;   // [256][64]
#pragma unroll
  for (int qg2 = 0; qg2 < 2; ++qg2)
#pragma unroll
    for (int dh = 0; dh < 2; ++dh)
#pragma unroll
      for (int r = 0; r < 16; ++r) {
        int qrow = wid * 64 + qg2 * 32 + (r & 3) + 8 * (r >> 2) + 4 * hi;
        cst[qrow * 64 + dh * 32 + ql] = f2bf(o[qg2][dh][r]);
      }
  __syncthreads();
  const int b = bh >> 4, h = bh & 15;
#pragma unroll
  for (int p = 0; p < 8; ++p) {
    int chunk = p * 256 + tid;          // 2048 chunks of 8 bf16
    int r = chunk >> 3, cc = (chunk & 7) * 8;
    u16* dst = ctx + ((size_t)(b * SEQ + q0 + r) * Ee + h * Dh + cc);
    *reinterpret_cast<bfrag*>(dst) = *reinterpret_cast<const bfrag*>(&cst[r * 64 + cc]);
  }
}

// ---------------- launch ----------------
extern "C" void kernel_launch(void* const* d_in, const int* in_sizes, int n_in,
                              void* d_out, int out_size, void* d_ws, size_t ws_size,
                              hipStream_t stream)
{
  const float* x  = (const float*)d_in[0];
  const float* Wq = (const float*)d_in[1];
  const float* bq = (const float*)d_in[2];
  const float* Wk = (const float*)d_in[3];
  const float* bk = (const float*)d_in[4];
  const float* Wv = (const float*)d_in[5];
  const float* bv = (const float*)d_in[6];
  const float* Wo = (const float*)d_in[7];
  const float* bo = (const float*)d_in[8];
  float* out = (float*)d_out;

  u16* ws  = (u16*)d_ws;
  u16* xb  = ws;                         // dead after QKV GEMM
  u16* wqb = ws + 8388608;
  u16* wkb = wqb + 1048576;
  u16* wvb = wkb + 1048576;
  u16* wob = wvb + 1048576;
  u16* qkv = wob + 1048576;              // 3 x [B,H,S,D]
  u16* q_  = qkv;
  u16* k_  = qkv + 8388608;
  u16* v_  = qkv + 2 * 8388608;
  u16* vt  = xb;                         // reuse xb: Vtp [B,H,D,S']
  u16* ctx = v_;                         // reuse V after transpose

  cast_all<<<12288, 256, 0, stream>>>(x, Wq, Wk, Wv, Wo, xb, wqb, wkb, wvb, wob);

  gemm_bt<0><<<dim3(64, 8, 3), 256, 0, stream>>>(xb, wqb, wkb, wvb, bq, bk, bv,
                                                 qkv, Ee, Ee);
  transpose_v<<<dim3(16, 64), 256, 0, stream>>>(v_, vt);
  attn_kernel<<<512, 256, 0, stream>>>(q_, k_, vt, ctx);
  gemm_bt<1><<<dim3(64, 8, 1), 256, 0, stream>>>(ctx, wob, wob, wob, bo, bo, bo,
                                                 out, Ee, Ee);
}

// Round 5
// 299.426 us; speedup vs baseline: 1.1741x; 1.0198x over previous
//
#include <hip/hip_runtime.h>
#include <hip/hip_bf16.h>
#include <stdint.h>

#define Bb 4
#define SEQ 2048
#define Ee 1024
#define Hh 16
#define Dh 64
#define Mm (Bb*SEQ)   // 8192

typedef __attribute__((ext_vector_type(8))) short bfrag;    // 8 bf16 (4 VGPRs)
typedef __attribute__((ext_vector_type(4))) float f32x4;
typedef __attribute__((ext_vector_type(16))) float f32x16;
typedef __attribute__((ext_vector_type(4))) unsigned u32x4;
typedef unsigned short u16;

__device__ __forceinline__ u16 f2bf(float x) {
  __hip_bfloat16 h = __float2bfloat16(x);
  return *reinterpret_cast<u16*>(&h);
}

__device__ __forceinline__ void gll16(const void* g, void* l) {
  __builtin_amdgcn_global_load_lds(
      (const __attribute__((address_space(1))) void*)g,
      (__attribute__((address_space(3))) void*)l, 16, 0, 0);
}

// ---------------- fused cast fp32 -> bf16 ----------------
__global__ __launch_bounds__(256) void cast_all(
    const float* __restrict__ x,  const float* __restrict__ wq,
    const float* __restrict__ wk, const float* __restrict__ wv,
    const float* __restrict__ wo,
    u16* __restrict__ xb, u16* __restrict__ wqb, u16* __restrict__ wkb,
    u16* __restrict__ wvb, u16* __restrict__ wob)
{
  int idx = blockIdx.x * 256 + threadIdx.x;
  const float* src; u16* dst; int off;
  if (idx < 2097152) { src = x; dst = xb; off = idx; }
  else {
    int t = idx - 2097152;
    int seg = t >> 18;
    off = t & 262143;
    src = (seg == 0) ? wq : (seg == 1) ? wk : (seg == 2) ? wv : wo;
    dst = (seg == 0) ? wqb : (seg == 1) ? wkb : (seg == 2) ? wvb : wob;
  }
  float4 v = reinterpret_cast<const float4*>(src)[off];
  ushort4 o;
  o.x = f2bf(v.x); o.y = f2bf(v.y); o.z = f2bf(v.z); o.w = f2bf(v.w);
  reinterpret_cast<ushort4*>(dst)[off] = o;
}

// ---------------- GEMM (m97 structure) ----------------
// OUTMODE 0: bf16 out scattered to [B,H,S,D]; z==0 (Q) additionally scaled by 1/8
//            (exact pow2 -> softsign denom becomes 1+|s|, inline-const).
// OUTMODE 1: fp32 out [M,N]
template<int OUTMODE>
__global__ __launch_bounds__(256) void gemm_bt(
    const u16* __restrict__ A,
    const u16* __restrict__ W0, const u16* __restrict__ W1, const u16* __restrict__ W2,
    const float* __restrict__ b0, const float* __restrict__ b1, const float* __restrict__ b2,
    void* __restrict__ outp, int K, int N)
{
  __shared__ __align__(16) u16 smem[16384];
  u16* As = smem;
  u16* Bs = smem + 8192;
  const int tid  = threadIdx.x;
  const int lane = tid & 63;
  const int wid  = tid >> 6;
  const int bm = blockIdx.x * 128;
  const int bn = blockIdx.y * 128;
  const int z  = blockIdx.z;
  const u16*  Wp = (z == 0) ? W0 : (z == 1) ? W1 : W2;
  const float* bp = (z == 0) ? b0 : (z == 1) ? b1 : b2;
  const int wr = (wid >> 1) * 64, wc = (wid & 1) * 64;
  const int lr = lane & 15, lk = (lane >> 4) * 8;
  f32x4 acc[4][4] = {};

  for (int kt = 0; kt < K; kt += 64) {
    __syncthreads();
#pragma unroll
    for (int p = 0; p < 4; ++p) {
      int flat = p * 2048 + tid * 8;
      int r = flat >> 6, c = flat & 63;
      gll16(A + (size_t)(bm + r) * K + kt + c, As + flat);
    }
#pragma unroll
    for (int p = 0; p < 4; ++p) {
      int flat = p * 2048 + tid * 8;
      int r = flat >> 6, c = flat & 63;
      gll16(Wp + (size_t)(bn + r) * K + kt + c, Bs + flat);
    }
    __syncthreads();
#pragma unroll
    for (int kk = 0; kk < 2; ++kk) {
      bfrag a[4], b[4];
#pragma unroll
      for (int i = 0; i < 4; ++i)
        a[i] = *reinterpret_cast<const bfrag*>(&As[(wr + i * 16 + lr) * 64 + kk * 32 + lk]);
#pragma unroll
      for (int j = 0; j < 4; ++j)
        b[j] = *reinterpret_cast<const bfrag*>(&Bs[(wc + j * 16 + lr) * 64 + kk * 32 + lk]);
#pragma unroll
      for (int i = 0; i < 4; ++i)
#pragma unroll
        for (int j = 0; j < 4; ++j)
          acc[i][j] = __builtin_amdgcn_mfma_f32_16x16x32_bf16(a[i], b[j], acc[i][j], 0, 0, 0);
    }
  }

  float bias[4];
#pragma unroll
  for (int j = 0; j < 4; ++j) bias[j] = bp[bn + wc + j * 16 + (lane & 15)];

  if (OUTMODE == 0) {
    const float scl = (z == 0) ? 0.125f : 1.0f;   // fold softsign's /8 into Q
    __syncthreads();
    u16* cst = smem;
#pragma unroll
    for (int i = 0; i < 4; ++i)
#pragma unroll
      for (int j = 0; j < 4; ++j)
#pragma unroll
        for (int e = 0; e < 4; ++e)
          cst[(wr + i * 16 + (lane >> 4) * 4 + e) * 128 + wc + j * 16 + (lane & 15)] =
              f2bf((acc[i][j][e] + bias[j]) * scl);
    __syncthreads();
    u16* outb = (u16*)outp + (size_t)z * (size_t)Mm * Ee;
#pragma unroll
    for (int p = 0; p < 8; ++p) {
      int chunk = p * 256 + tid;
      int r = chunk >> 4;
      int c = (chunk & 15) * 8;
      int m = bm + r, f = bn + c;
      u16* dst = outb + ((((size_t)(m >> 11) * Hh + (f >> 6)) * SEQ + (m & 2047)) * Dh + (f & 63));
      *reinterpret_cast<bfrag*>(dst) = *reinterpret_cast<const bfrag*>(&cst[r * 128 + c]);
    }
  } else {
    float* outf = (float*)outp;
    float* cf = reinterpret_cast<float*>(smem);
#pragma unroll
    for (int half = 0; half < 2; ++half) {
      __syncthreads();
      if ((wid >> 1) == half) {
#pragma unroll
        for (int i = 0; i < 4; ++i)
#pragma unroll
          for (int j = 0; j < 4; ++j)
#pragma unroll
            for (int e = 0; e < 4; ++e)
              cf[(i * 16 + (lane >> 4) * 4 + e) * 128 + wc + j * 16 + (lane & 15)] =
                  acc[i][j][e] + bias[j];
      }
      __syncthreads();
#pragma unroll
      for (int p = 0; p < 8; ++p) {
        int chunk = p * 256 + tid;
        int r = chunk >> 5;
        int c = (chunk & 31) * 4;
        *reinterpret_cast<float4*>(&outf[(size_t)(bm + half * 64 + r) * N + bn + c]) =
            *reinterpret_cast<const float4*>(&cf[r * 128 + c]);
      }
    }
  }
}

// ---------------- V transpose+permute: [B,H,S,D] -> [B,H,D,S'] -----------------
// s' = s with bits 2,3 swapped (involution): bakes the PV k-permutation so the
// swapped-QK^T output registers feed PV's A-operand with no cross-lane ops.
__global__ __launch_bounds__(256) void transpose_v(const u16* __restrict__ v,
                                                   u16* __restrict__ vt)
{
  __shared__ __align__(16) u16 lds[8192];
  const int tid = threadIdx.x;
  const int bh = blockIdx.y;
  const int st = blockIdx.x * 128;
  const u16* vb = v + (size_t)bh * SEQ * Dh;
#pragma unroll
  for (int p = 0; p < 4; ++p) {
    int flat = p * 2048 + tid * 8;
    int s = flat >> 6, dp = flat & 63;
    int dl = dp ^ (((s >> 3) & 7) << 3);        // pre-swizzled global source
    gll16(vb + (size_t)(st + s) * Dh + dl, lds + flat);
  }
  __syncthreads();
  u16* vtb = vt + (size_t)bh * Dh * SEQ;
#pragma unroll
  for (int p = 0; p < 4; ++p) {
    int chunk = p * 256 + tid;      // sc = chunk&15 (s'-octet), d = chunk>>4
    int sc = chunk & 15, d = chunk >> 4;
    bfrag o;
#pragma unroll
    for (int e = 0; e < 8; ++e) {
      int sp = sc * 8 + e;                                       // s' local
      int ss = (sp & ~12) | ((sp & 4) << 1) | ((sp & 8) >> 1);   // swap bits 2,3
      int X = ((ss >> 3) & 7) << 3;
      o[e] = (short)lds[ss * 64 + (d ^ X)];
    }
    *reinterpret_cast<bfrag*>(&vtb[(size_t)d * SEQ + st + sc * 8]) = o;
  }
}

// ---------------- fused attention (softsign), swapped-QK^T 32x32 ---------------
// 1024 blocks (4/CU), 4 waves x 32 q-rows. K/V 64-tiles double-buffered in LDS
// packed as [32 lds-rows][128 cols] with 4-bit XOR swizzle (16-slot spread).
// Q pre-scaled by 1/8 -> P = s/(1+|s|), truncation-packed via v_perm.
__global__ __launch_bounds__(256, 4) void attn_kernel(
    const u16* __restrict__ qg_, const u16* __restrict__ kg,
    const u16* __restrict__ vtg, u16* __restrict__ ctx)
{
  __shared__ __align__(16) u16 smem[16384];   // K dbuf 2x4096 | V dbuf 2x4096 (32 KB)
  const int tid  = threadIdx.x;
  const int lane = tid & 63;
  const int wid  = tid >> 6;
  const int ql = lane & 31;
  const int hi = lane >> 5;

  // XCD-bijective swizzle: 1024 wgs, 128/XCD -> 8 consecutive bh per XCD (K/V L2-fit)
  const int orig = blockIdx.x;
  const int swz  = (orig & 7) * 128 + (orig >> 3);
  const int bh = swz >> 4;
  const int q0 = (swz & 15) * 128;

  const u16* qb  = qg_ + (size_t)bh * SEQ * Dh;
  const u16* kb  = kg  + (size_t)bh * SEQ * Dh;
  const u16* vtb = vtg + (size_t)bh * Dh * SEQ;

  // Q frags (B operand): lane -> Q[q0+wid*32+ql][db*16+hi*8 .. +7]  (pre-scaled /8)
  bfrag qf[4];
#pragma unroll
  for (int db = 0; db < 4; ++db)
    qf[db] = *reinterpret_cast<const bfrag*>(
        &qb[(size_t)(q0 + wid * 32 + ql) * Dh + db * 16 + hi * 8]);

  // staging source offsets (32-bit, precomputed; dest stays lane-linear)
  int koff[2], voff[2];
#pragma unroll
  for (int p = 0; p < 2; ++p) {
    int f = p * 2048 + tid * 8;
    int lrow = f >> 7;
    int log7 = (f & 127) ^ ((lrow & 15) << 3);
    int r = lrow * 2 + (log7 >> 6);
    int c = log7 & 63;
    koff[p] = r * 64 + c;        // K tile: row r (k), col c (d); + kt*64 per tile
    voff[p] = r * SEQ + c;       // Vt tile: row r (d), col c (s'); + kt per tile
  }

  f32x16 o[2] = {};   // o[dh]: rows=q (C-layout), cols=d

  auto stage = [&](int kt, int buf) {
#pragma unroll
    for (int p = 0; p < 2; ++p)
      gll16(kb + (size_t)kt * 64 + koff[p], smem + buf * 4096 + p * 2048 + tid * 8);
#pragma unroll
    for (int p = 0; p < 2; ++p)
      gll16(vtb + kt + voff[p], smem + 8192 + buf * 4096 + p * 2048 + tid * 8);
  };

  stage(0, 0);
  __syncthreads();

  for (int ti = 0; ti < 32; ++ti) {
    const int cur = ti & 1;
    if (ti < 31) stage((ti + 1) * 64, cur ^ 1);   // prefetch overlaps compute
    const u16* Kb = smem + cur * 4096;
    const u16* Vb = smem + 8192 + cur * 4096;

#pragma unroll
    for (int kh = 0; kh < 2; ++kh) {
      // S^T = mfma(A=K, B=Q): lane owns q=ql column; accumulate over 4 d-blocks
      f32x16 s = {};
      __builtin_amdgcn_s_setprio(1);
#pragma unroll
      for (int db = 0; db < 4; ++db) {
        const int krow = kh * 32 + ql;
        const int lr2 = krow >> 1;
        const int log7 = ((krow & 1) << 6) | (db * 16 + hi * 8);
        bfrag ka = *reinterpret_cast<const bfrag*>(
            &Kb[lr2 * 128 + (log7 ^ ((lr2 & 15) << 3))]);
        s = __builtin_amdgcn_mfma_f32_32x32x16_bf16(ka, qf[db], s, 0, 0, 0);
      }
      __builtin_amdgcn_s_setprio(0);

      // softsign: P = s/(1+|s|); truncation-pack 2 f32 -> 1 u32 via v_perm
      unsigned pw[8];
#pragma unroll
      for (int r = 0; r < 8; ++r) {
        float a = s[2 * r], b = s[2 * r + 1];
        float pa_ = a * __builtin_amdgcn_rcpf(1.0f + __builtin_fabsf(a));
        float pb_ = b * __builtin_amdgcn_rcpf(1.0f + __builtin_fabsf(b));
        pw[r] = __builtin_amdgcn_perm(__builtin_bit_cast(unsigned, pb_),
                                      __builtin_bit_cast(unsigned, pa_),
                                      0x07060302u);
      }
      u32x4 w0 = {pw[0], pw[1], pw[2], pw[3]};
      u32x4 w1 = {pw[4], pw[5], pw[6], pw[7]};
      bfrag pa0 = __builtin_bit_cast(bfrag, w0);
      bfrag pa1 = __builtin_bit_cast(bfrag, w1);

      // O += P @ V  (V k-rows pre-permuted to match S^T register order)
      __builtin_amdgcn_s_setprio(1);
#pragma unroll
      for (int tt = 0; tt < 2; ++tt)
#pragma unroll
        for (int dh = 0; dh < 2; ++dh) {
          const int vrow = dh * 32 + ql;
          const int lr2 = vrow >> 1;
          const int log7 = ((vrow & 1) << 6) | (kh * 32 + tt * 16 + hi * 8);
          bfrag vb = *reinterpret_cast<const bfrag*>(
              &Vb[lr2 * 128 + (log7 ^ ((lr2 & 15) << 3))]);
          o[dh] = __builtin_amdgcn_mfma_f32_32x32x16_bf16(tt ? pa1 : pa0, vb, o[dh], 0, 0, 0);
        }
      __builtin_amdgcn_s_setprio(0);
    }
    __syncthreads();   // drains prefetch vmcnt + releases buffers
  }

  // epilogue: O rows q=(r&3)+8*(r>>2)+4*hi, col d=dh*32+ql; via LDS to coalesce
  u16* cst = smem;   // [128][64] = 16 KB
#pragma unroll
  for (int dh = 0; dh < 2; ++dh)
#pragma unroll
    for (int r = 0; r < 16; ++r) {
      int qrow = wid * 32 + (r & 3) + 8 * (r >> 2) + 4 * hi;
      cst[qrow * 64 + dh * 32 + ql] = f2bf(o[dh][r]);
    }
  __syncthreads();
  const int b = bh >> 4, h = bh & 15;
#pragma unroll
  for (int p = 0; p < 4; ++p) {
    int chunk = p * 256 + tid;          // 1024 chunks of 8 bf16
    int r = chunk >> 3, cc = (chunk & 7) * 8;
    u16* dst = ctx + ((size_t)(b * SEQ + q0 + r) * Ee + h * Dh + cc);
    *reinterpret_cast<bfrag*>(dst) = *reinterpret_cast<const bfrag*>(&cst[r * 64 + cc]);
  }
}

// ---------------- launch ----------------
extern "C" void kernel_launch(void* const* d_in, const int* in_sizes, int n_in,
                              void* d_out, int out_size, void* d_ws, size_t ws_size,
                              hipStream_t stream)
{
  const float* x  = (const float*)d_in[0];
  const float* Wq = (const float*)d_in[1];
  const float* bq = (const float*)d_in[2];
  const float* Wk = (const float*)d_in[3];
  const float* bk = (const float*)d_in[4];
  const float* Wv = (const float*)d_in[5];
  const float* bv = (const float*)d_in[6];
  const float* Wo = (const float*)d_in[7];
  const float* bo = (const float*)d_in[8];
  float* out = (float*)d_out;

  u16* ws  = (u16*)d_ws;
  u16* xb  = ws;                         // dead after QKV GEMM
  u16* wqb = ws + 8388608;
  u16* wkb = wqb + 1048576;
  u16* wvb = wkb + 1048576;
  u16* wob = wvb + 1048576;
  u16* qkv = wob + 1048576;              // 3 x [B,H,S,D]
  u16* q_  = qkv;
  u16* k_  = qkv + 8388608;
  u16* v_  = qkv + 2 * 8388608;
  u16* vt  = xb;                         // reuse xb: Vtp [B,H,D,S']
  u16* ctx = v_;                         // reuse V after transpose

  cast_all<<<12288, 256, 0, stream>>>(x, Wq, Wk, Wv, Wo, xb, wqb, wkb, wvb, wob);

  gemm_bt<0><<<dim3(64, 8, 3), 256, 0, stream>>>(xb, wqb, wkb, wvb, bq, bk, bv,
                                                 qkv, Ee, Ee);
  transpose_v<<<dim3(16, 64), 256, 0, stream>>>(v_, vt);
  attn_kernel<<<1024, 256, 0, stream>>>(q_, k_, vt, ctx);
  gemm_bt<1><<<dim3(64, 8, 1), 256, 0, stream>>>(ctx, wob, wob, wob, bo, bo, bo,
                                                 out, Ee, Ee);
}

// Round 6
// 255.969 us; speedup vs baseline: 1.3735x; 1.1698x over previous
//
#include <hip/hip_runtime.h>
#include <hip/hip_bf16.h>
#include <stdint.h>

#define Bb 4
#define SEQ 2048
#define Ee 1024
#define Hh 16
#define Dh 64
#define Mm (Bb*SEQ)   // 8192

typedef __attribute__((ext_vector_type(8))) short bfrag;    // 8 bf16 (4 VGPRs)
typedef __attribute__((ext_vector_type(4))) float f32x4;
typedef __attribute__((ext_vector_type(16))) float f32x16;
typedef __attribute__((ext_vector_type(4))) unsigned u32x4;
typedef unsigned short u16;

__device__ __forceinline__ u16 f2bf(float x) {
  __hip_bfloat16 h = __float2bfloat16(x);
  return *reinterpret_cast<u16*>(&h);
}

__device__ __forceinline__ void gll16(const void* g, void* l) {
  __builtin_amdgcn_global_load_lds(
      (const __attribute__((address_space(1))) void*)g,
      (__attribute__((address_space(3))) void*)l, 16, 0, 0);
}

// ---------------- fused cast fp32 -> bf16 ----------------
__global__ __launch_bounds__(256) void cast_all(
    const float* __restrict__ x,  const float* __restrict__ wq,
    const float* __restrict__ wk, const float* __restrict__ wv,
    const float* __restrict__ wo,
    u16* __restrict__ xb, u16* __restrict__ wqb, u16* __restrict__ wkb,
    u16* __restrict__ wvb, u16* __restrict__ wob)
{
  int idx = blockIdx.x * 256 + threadIdx.x;
  const float* src; u16* dst; int off;
  if (idx < 2097152) { src = x; dst = xb; off = idx; }
  else {
    int t = idx - 2097152;
    int seg = t >> 18;
    off = t & 262143;
    src = (seg == 0) ? wq : (seg == 1) ? wk : (seg == 2) ? wv : wo;
    dst = (seg == 0) ? wqb : (seg == 1) ? wkb : (seg == 2) ? wvb : wob;
  }
  float4 v = reinterpret_cast<const float4*>(src)[off];
  ushort4 o;
  o.x = f2bf(v.x); o.y = f2bf(v.y); o.z = f2bf(v.z); o.w = f2bf(v.w);
  reinterpret_cast<ushort4*>(dst)[off] = o;
}

// ---------------- GEMM: C[m,f] = sum_e A[m,e]*W[f,e] + bias[f] ----------------
// 128x128 tile, BK=64, 4 waves. Double-buffered LDS (prefetch t+1 before compute t),
// XOR-8 swizzle on staging (pre-swizzled global source) + reads, setprio on MFMA.
// OUTMODE 0: z==0 Q (scaled 1/8) / z==1 K -> scatter [B,H,S,D];
//            z==2 V -> fused transpose+permute to [B,H,D,S'] (s' = s bits2,3 swapped)
// OUTMODE 1: fp32 out [M,N]
template<int OUTMODE>
__global__ __launch_bounds__(256) void gemm_bt(
    const u16* __restrict__ A,
    const u16* __restrict__ W0, const u16* __restrict__ W1, const u16* __restrict__ W2,
    const float* __restrict__ b0, const float* __restrict__ b1, const float* __restrict__ b2,
    void* __restrict__ outp, u16* __restrict__ vt, int K, int N)
{
  __shared__ __align__(16) u16 smem[32768];   // 64 KB: 2 slots x (As 8192 | Bs 8192)
  const int tid  = threadIdx.x;
  const int lane = tid & 63;
  const int wid  = tid >> 6;
  const int bm = blockIdx.x * 128;
  const int bn = blockIdx.y * 128;
  const int z  = blockIdx.z;
  const u16*  Wp = (z == 0) ? W0 : (z == 1) ? W1 : W2;
  const float* bp = (z == 0) ? b0 : (z == 1) ? b1 : b2;
  const int wr = (wid >> 1) * 64, wc = (wid & 1) * 64;
  const int lr = lane & 15, lk = (lane >> 4) * 8;
  const int kx = (lr & 7) << 3;               // read-side XOR key (row&7 == lr&7)

  // staging source offsets: swizzled global col, linear LDS dest (rule 21)
  size_t aoff[4], boff[4];
#pragma unroll
  for (int p = 0; p < 4; ++p) {
    int flat = p * 2048 + tid * 8;
    int r = flat >> 6, c = flat & 63;
    int cs = c ^ ((r & 7) << 3);
    aoff[p] = (size_t)(bm + r) * K + cs;
    boff[p] = (size_t)(bn + r) * K + cs;
  }

  f32x4 acc[4][4] = {};

  auto stage = [&](int kt, int s) {
    u16* As = smem + s * 16384;
    u16* Bs = As + 8192;
#pragma unroll
    for (int p = 0; p < 4; ++p)
      gll16(A + aoff[p] + kt, As + p * 2048 + tid * 8);
#pragma unroll
    for (int p = 0; p < 4; ++p)
      gll16(Wp + boff[p] + kt, Bs + p * 2048 + tid * 8);
  };

  const int NT = K >> 6;
  stage(0, 0);
  __syncthreads();
  for (int t = 0; t < NT; ++t) {
    const int cur = t & 1;
    if (t + 1 < NT) stage((t + 1) << 6, cur ^ 1);   // prefetch overlaps compute
    const u16* As = smem + cur * 16384;
    const u16* Bs = As + 8192;
#pragma unroll
    for (int kk = 0; kk < 2; ++kk) {
      bfrag a[4], b[4];
      const int col = (kk * 32 + lk) ^ kx;
#pragma unroll
      for (int i = 0; i < 4; ++i)
        a[i] = *reinterpret_cast<const bfrag*>(&As[(wr + i * 16 + lr) * 64 + col]);
#pragma unroll
      for (int j = 0; j < 4; ++j)
        b[j] = *reinterpret_cast<const bfrag*>(&Bs[(wc + j * 16 + lr) * 64 + col]);
      __builtin_amdgcn_s_setprio(1);
#pragma unroll
      for (int i = 0; i < 4; ++i)
#pragma unroll
        for (int j = 0; j < 4; ++j)
          acc[i][j] = __builtin_amdgcn_mfma_f32_16x16x32_bf16(a[i], b[j], acc[i][j], 0, 0, 0);
      __builtin_amdgcn_s_setprio(0);
    }
    __syncthreads();   // drains prefetch vmcnt + releases the other slot
  }

  float bias[4];
#pragma unroll
  for (int j = 0; j < 4; ++j) bias[j] = bp[bn + wc + j * 16 + (lane & 15)];

  if (OUTMODE == 0) {
    const float scl = (z == 0) ? 0.125f : 1.0f;   // fold softsign's /8 into Q
    u16* cst = smem;   // [128][128] bf16, XOR-8 swizzled cols
#pragma unroll
    for (int i = 0; i < 4; ++i)
#pragma unroll
      for (int j = 0; j < 4; ++j)
#pragma unroll
        for (int e = 0; e < 4; ++e) {
          int row = wr + i * 16 + (lane >> 4) * 4 + e;
          int c2  = wc + j * 16 + (lane & 15);
          cst[row * 128 + (c2 ^ ((row & 7) << 3))] = f2bf((acc[i][j][e] + bias[j]) * scl);
        }
    __syncthreads();
    if (z < 2) {
      u16* outb = (u16*)outp + (size_t)z * (size_t)Mm * Ee;
#pragma unroll
      for (int p = 0; p < 8; ++p) {
        int chunk = p * 256 + tid;        // 2048 chunks of 8 bf16
        int r = chunk >> 4;
        int c = (chunk & 15) * 8;
        int m = bm + r, f = bn + c;
        u16* dst = outb + ((((size_t)(m >> 11) * Hh + (f >> 6)) * SEQ + (m & 2047)) * Dh + (f & 63));
        *reinterpret_cast<bfrag*>(dst) =
            *reinterpret_cast<const bfrag*>(&cst[r * 128 + (c ^ ((r & 7) << 3))]);
      }
    } else {
      // V: write transposed+permuted [B,H,D,S'] directly (replaces transpose_v kernel)
      const int bq = bm >> 11;
      const int s_base = bm & 2047;
#pragma unroll
      for (int p = 0; p < 8; ++p) {
        int chunk = p * 256 + tid;        // 2048: d = chunk>>4 (0..127), sc = chunk&15
        int d = chunk >> 4, sc = chunk & 15;
        int f = bn + d;
        int h = f >> 6, dl = f & 63;
        bfrag o;
#pragma unroll
        for (int e = 0; e < 8; ++e) {
          int sp = sc * 8 + e;                                       // s' local
          int ss = (sp & ~12) | ((sp & 4) << 1) | ((sp & 8) >> 1);   // swap bits 2,3
          o[e] = (short)cst[ss * 128 + (d ^ ((ss & 7) << 3))];
        }
        *reinterpret_cast<bfrag*>(
            &vt[((size_t)((bq * Hh + h) * Dh + dl)) * SEQ + s_base + sc * 8]) = o;
      }
    }
  } else {
    float* outf = (float*)outp;
    float* cf = reinterpret_cast<float*>(smem);   // [64][128] fp32 = 32 KB
#pragma unroll
    for (int half = 0; half < 2; ++half) {
      __syncthreads();
      if ((wid >> 1) == half) {
#pragma unroll
        for (int i = 0; i < 4; ++i)
#pragma unroll
          for (int j = 0; j < 4; ++j)
#pragma unroll
            for (int e = 0; e < 4; ++e)
              cf[(i * 16 + (lane >> 4) * 4 + e) * 128 + wc + j * 16 + (lane & 15)] =
                  acc[i][j][e] + bias[j];
      }
      __syncthreads();
#pragma unroll
      for (int p = 0; p < 8; ++p) {
        int chunk = p * 256 + tid;
        int r = chunk >> 5;
        int c = (chunk & 31) * 4;
        *reinterpret_cast<float4*>(&outf[(size_t)(bm + half * 64 + r) * N + bn + c]) =
            *reinterpret_cast<const float4*>(&cf[r * 128 + c]);
      }
    }
  }
}

// ---------------- fused attention (softsign), swapped-QK^T 32x32 ---------------
// 1024 blocks (4/CU), 4 waves x 32 q-rows. K/V 64-tiles double-buffered in LDS
// packed as [32 lds-rows][128 cols] with 4-bit XOR swizzle (16-slot spread).
// Q pre-scaled by 1/8 -> P = s/(1+|s|), truncation-packed via v_perm.
__global__ __launch_bounds__(256, 4) void attn_kernel(
    const u16* __restrict__ qg_, const u16* __restrict__ kg,
    const u16* __restrict__ vtg, u16* __restrict__ ctx)
{
  __shared__ __align__(16) u16 smem[16384];   // K dbuf 2x4096 | V dbuf 2x4096 (32 KB)
  const int tid  = threadIdx.x;
  const int lane = tid & 63;
  const int wid  = tid >> 6;
  const int ql = lane & 31;
  const int hi = lane >> 5;

  // XCD-bijective swizzle: 1024 wgs, 128/XCD -> 8 consecutive bh per XCD (K/V L2-fit)
  const int orig = blockIdx.x;
  const int swz  = (orig & 7) * 128 + (orig >> 3);
  const int bh = swz >> 4;
  const int q0 = (swz & 15) * 128;

  const u16* qb  = qg_ + (size_t)bh * SEQ * Dh;
  const u16* kb  = kg  + (size_t)bh * SEQ * Dh;
  const u16* vtb = vtg + (size_t)bh * Dh * SEQ;

  // Q frags (B operand): lane -> Q[q0+wid*32+ql][db*16+hi*8 .. +7]  (pre-scaled /8)
  bfrag qf[4];
#pragma unroll
  for (int db = 0; db < 4; ++db)
    qf[db] = *reinterpret_cast<const bfrag*>(
        &qb[(size_t)(q0 + wid * 32 + ql) * Dh + db * 16 + hi * 8]);

  // staging source offsets (32-bit, precomputed; dest stays lane-linear)
  int koff[2], voff[2];
#pragma unroll
  for (int p = 0; p < 2; ++p) {
    int f = p * 2048 + tid * 8;
    int lrow = f >> 7;
    int log7 = (f & 127) ^ ((lrow & 15) << 3);
    int r = lrow * 2 + (log7 >> 6);
    int c = log7 & 63;
    koff[p] = r * 64 + c;        // K tile: row r (k), col c (d); + kt*64 per tile
    voff[p] = r * SEQ + c;       // Vt tile: row r (d), col c (s'); + kt per tile
  }

  f32x16 o[2] = {};   // o[dh]: rows=q (C-layout), cols=d

  auto stage = [&](int kt, int buf) {
#pragma unroll
    for (int p = 0; p < 2; ++p)
      gll16(kb + (size_t)kt * 64 + koff[p], smem + buf * 4096 + p * 2048 + tid * 8);
#pragma unroll
    for (int p = 0; p < 2; ++p)
      gll16(vtb + kt + voff[p], smem + 8192 + buf * 4096 + p * 2048 + tid * 8);
  };

  stage(0, 0);
  __syncthreads();

  for (int ti = 0; ti < 32; ++ti) {
    const int cur = ti & 1;
    if (ti < 31) stage((ti + 1) * 64, cur ^ 1);   // prefetch overlaps compute
    const u16* Kb = smem + cur * 4096;
    const u16* Vb = smem + 8192 + cur * 4096;

#pragma unroll
    for (int kh = 0; kh < 2; ++kh) {
      // S^T = mfma(A=K, B=Q): lane owns q=ql column; accumulate over 4 d-blocks
      f32x16 s = {};
      __builtin_amdgcn_s_setprio(1);
#pragma unroll
      for (int db = 0; db < 4; ++db) {
        const int krow = kh * 32 + ql;
        const int lr2 = krow >> 1;
        const int log7 = ((krow & 1) << 6) | (db * 16 + hi * 8);
        bfrag ka = *reinterpret_cast<const bfrag*>(
            &Kb[lr2 * 128 + (log7 ^ ((lr2 & 15) << 3))]);
        s = __builtin_amdgcn_mfma_f32_32x32x16_bf16(ka, qf[db], s, 0, 0, 0);
      }
      __builtin_amdgcn_s_setprio(0);

      // softsign: P = s/(1+|s|); truncation-pack 2 f32 -> 1 u32 via v_perm
      unsigned pw[8];
#pragma unroll
      for (int r = 0; r < 8; ++r) {
        float a = s[2 * r], b = s[2 * r + 1];
        float pa_ = a * __builtin_amdgcn_rcpf(1.0f + __builtin_fabsf(a));
        float pb_ = b * __builtin_amdgcn_rcpf(1.0f + __builtin_fabsf(b));
        pw[r] = __builtin_amdgcn_perm(__builtin_bit_cast(unsigned, pb_),
                                      __builtin_bit_cast(unsigned, pa_),
                                      0x07060302u);
      }
      u32x4 w0 = {pw[0], pw[1], pw[2], pw[3]};
      u32x4 w1 = {pw[4], pw[5], pw[6], pw[7]};
      bfrag pa0 = __builtin_bit_cast(bfrag, w0);
      bfrag pa1 = __builtin_bit_cast(bfrag, w1);

      // O += P @ V  (V k-rows pre-permuted to match S^T register order)
      __builtin_amdgcn_s_setprio(1);
#pragma unroll
      for (int tt = 0; tt < 2; ++tt)
#pragma unroll
        for (int dh = 0; dh < 2; ++dh) {
          const int vrow = dh * 32 + ql;
          const int lr2 = vrow >> 1;
          const int log7 = ((vrow & 1) << 6) | (kh * 32 + tt * 16 + hi * 8);
          bfrag vb = *reinterpret_cast<const bfrag*>(
              &Vb[lr2 * 128 + (log7 ^ ((lr2 & 15) << 3))]);
          o[dh] = __builtin_amdgcn_mfma_f32_32x32x16_bf16(tt ? pa1 : pa0, vb, o[dh], 0, 0, 0);
        }
      __builtin_amdgcn_s_setprio(0);
    }
    __syncthreads();   // drains prefetch vmcnt + releases buffers
  }

  // epilogue: O rows q=(r&3)+8*(r>>2)+4*hi, col d=dh*32+ql; via LDS to coalesce
  u16* cst = smem;   // [128][64] = 16 KB
#pragma unroll
  for (int dh = 0; dh < 2; ++dh)
#pragma unroll
    for (int r = 0; r < 16; ++r) {
      int qrow = wid * 32 + (r & 3) + 8 * (r >> 2) + 4 * hi;
      cst[qrow * 64 + dh * 32 + ql] = f2bf(o[dh][r]);
    }
  __syncthreads();
  const int b = bh >> 4, h = bh & 15;
#pragma unroll
  for (int p = 0; p < 4; ++p) {
    int chunk = p * 256 + tid;          // 1024 chunks of 8 bf16
    int r = chunk >> 3, cc = (chunk & 7) * 8;
    u16* dst = ctx + ((size_t)(b * SEQ + q0 + r) * Ee + h * Dh + cc);
    *reinterpret_cast<bfrag*>(dst) = *reinterpret_cast<const bfrag*>(&cst[r * 64 + cc]);
  }
}

// ---------------- launch ----------------
extern "C" void kernel_launch(void* const* d_in, const int* in_sizes, int n_in,
                              void* d_out, int out_size, void* d_ws, size_t ws_size,
                              hipStream_t stream)
{
  const float* x  = (const float*)d_in[0];
  const float* Wq = (const float*)d_in[1];
  const float* bq = (const float*)d_in[2];
  const float* Wk = (const float*)d_in[3];
  const float* bk = (const float*)d_in[4];
  const float* Wv = (const float*)d_in[5];
  const float* bv = (const float*)d_in[6];
  const float* Wo = (const float*)d_in[7];
  const float* bo = (const float*)d_in[8];
  float* out = (float*)d_out;

  u16* ws  = (u16*)d_ws;
  u16* xb  = ws;                         // A input; dead after QKV GEMM -> reused as ctx
  u16* wqb = ws + 8388608;
  u16* wkb = wqb + 1048576;
  u16* wvb = wkb + 1048576;
  u16* wob = wvb + 1048576;
  u16* qkv = wob + 1048576;              // Q,K in [B,H,S,D]; slot 2 = Vt [B,H,D,S']
  u16* q_  = qkv;
  u16* k_  = qkv + 8388608;
  u16* vt  = qkv + 2 * 8388608;          // V written transposed by gemm z==2
  u16* ctx = xb;                         // reuse xb after QKV gemm

  cast_all<<<12288, 256, 0, stream>>>(x, Wq, Wk, Wv, Wo, xb, wqb, wkb, wvb, wob);

  // QKV projections; z==2 fuses the V transpose (writes vt)
  gemm_bt<0><<<dim3(64, 8, 3), 256, 0, stream>>>(xb, wqb, wkb, wvb, bq, bk, bv,
                                                 qkv, vt, Ee, Ee);
  // fused softsign attention -> ctx [B,S,E] bf16
  attn_kernel<<<1024, 256, 0, stream>>>(q_, k_, vt, ctx);
  // output projection, fp32 out
  gemm_bt<1><<<dim3(64, 8, 1), 256, 0, stream>>>(ctx, wob, wob, wob, bo, bo, bo,
                                                 out, nullptr, Ee, Ee);
}